// Round 1
// baseline (2206.191 us; speedup 1.0000x reference)
//
#include <hip/hip_runtime.h>
#include <math.h>

#define HH 128
#define WWD 128
#define HWSZ (HH*WWD)
#define BB 8
#define CC 64
#define C2 216

// wt[r*O + o] = w[o*CiK + r]   (r = ci*9+k)
__global__ void transpose_w_k(const float* __restrict__ w, float* __restrict__ wt, int O, int CiK) {
    int idx = blockIdx.x * 256 + threadIdx.x;
    if (idx >= O * CiK) return;
    int o = idx / CiK, r = idx % CiK;
    wt[r * O + o] = w[idx];
}

// Direct 3x3 conv, pad=1. One thread per output pixel, COT output channels per thread.
// Weight reads are wave-uniform (scalar loads).
template<int COT>
__global__ void conv3x3_k(const float* __restrict__ x, const float* __restrict__ wt,
                          const float* __restrict__ bias, float* __restrict__ y,
                          int Cin, int Cout) {
    int p = blockIdx.x * 256 + threadIdx.x;       // 0 .. B*HW-1
    int b = p >> 14;
    int hw = p & 16383;
    int h = hw >> 7;
    int w = hw & 127;
    int co0 = blockIdx.y * COT;
    float acc[COT];
#pragma unroll
    for (int j = 0; j < COT; j++) acc[j] = bias[co0 + j];
#pragma unroll 1
    for (int ci = 0; ci < Cin; ci++) {
        const float* xb = x + ((size_t)b * Cin + ci) * HWSZ;
#pragma unroll
        for (int k = 0; k < 9; k++) {
            int hh = h + k / 3 - 1;
            int ww = w + k % 3 - 1;
            float xv = 0.f;
            if ((unsigned)hh < (unsigned)HH && (unsigned)ww < (unsigned)WWD)
                xv = xb[hh * WWD + ww];
            const float* wp = wt + (ci * 9 + k) * Cout + co0;   // uniform
#pragma unroll
            for (int j = 0; j < COT; j++) acc[j] = fmaf(wp[j], xv, acc[j]);
        }
    }
    float* yb = y + ((size_t)b * Cout + co0) * HWSZ + hw;
#pragma unroll
    for (int j = 0; j < COT; j++) yb[(size_t)j * HWSZ] = acc[j];
}

// Modulated deformable conv. One thread per output pixel, all 64 output channels.
// off layout: [b][216][H][W]; dy ch = dg*18+2k, dx ch = dg*18+2k+1, mask ch = 144+dg*9+k.
__global__ void deform_k(const float* __restrict__ x, const float* __restrict__ off,
                         const float* __restrict__ wt, const float* __restrict__ bias,
                         float* __restrict__ out) {
    int p = blockIdx.x * 256 + threadIdx.x;
    int b = p >> 14;
    int hw = p & 16383;
    int h = hw >> 7;
    int w = hw & 127;
    float acc[CC];
#pragma unroll
    for (int o = 0; o < CC; o++) acc[o] = bias[o];
    const float* offb = off + (size_t)b * C2 * HWSZ + hw;
#pragma unroll 1
    for (int dg = 0; dg < 8; dg++) {
#pragma unroll 1
        for (int k = 0; k < 9; k++) {
            float dy = offb[(size_t)(dg * 18 + 2 * k) * HWSZ];
            float dx = offb[(size_t)(dg * 18 + 2 * k + 1) * HWSZ];
            float mr = offb[(size_t)(144 + dg * 9 + k) * HWSZ];
            float m = 1.f / (1.f + __expf(-mr));
            float py = dy + (float)(h + k / 3 - 1);
            float px = dx + (float)(w + k % 3 - 1);
            float fy = floorf(py), fx = floorf(px);
            int y0 = (int)fy, x0 = (int)fx;
            int y1 = y0 + 1, x1 = x0 + 1;
            float ly = py - fy, lx = px - fx;
            bool vy0 = (unsigned)y0 < (unsigned)HH, vy1 = (unsigned)y1 < (unsigned)HH;
            bool vx0 = (unsigned)x0 < (unsigned)WWD, vx1 = (unsigned)x1 < (unsigned)WWD;
            float w00 = (vy0 && vx0) ? (1.f - ly) * (1.f - lx) * m : 0.f;
            float w01 = (vy0 && vx1) ? (1.f - ly) * lx * m : 0.f;
            float w10 = (vy1 && vx0) ? ly * (1.f - lx) * m : 0.f;
            float w11 = (vy1 && vx1) ? ly * lx * m : 0.f;
            int y0c = min(max(y0, 0), HH - 1), y1c = min(max(y1, 0), HH - 1);
            int x0c = min(max(x0, 0), WWD - 1), x1c = min(max(x1, 0), WWD - 1);
            int i00 = y0c * WWD + x0c, i01 = y0c * WWD + x1c;
            int i10 = y1c * WWD + x0c, i11 = y1c * WWD + x1c;
#pragma unroll
            for (int c = 0; c < 8; c++) {
                int ch = dg * 8 + c;
                const float* xb = x + ((size_t)b * CC + ch) * HWSZ;
                float v = w00 * xb[i00] + w01 * xb[i01] + w10 * xb[i10] + w11 * xb[i11];
                const float* wp = wt + (ch * 9 + k) * CC;   // uniform
#pragma unroll
                for (int o = 0; o < CC; o++) acc[o] = fmaf(wp[o], v, acc[o]);
            }
        }
    }
    float* ob = out + (size_t)b * CC * HWSZ + hw;
#pragma unroll
    for (int o = 0; o < CC; o++) ob[(size_t)o * HWSZ] = acc[o];
}

extern "C" void kernel_launch(void* const* d_in, const int* in_sizes, int n_in,
                              void* d_out, int out_size, void* d_ws, size_t ws_size,
                              hipStream_t stream) {
    const float* cat_fea = (const float*)d_in[0];
    const float* f_fea   = (const float*)d_in[1];
    const float* w_off2d = (const float*)d_in[2];
    const float* b_off2d = (const float*)d_in[3];
    const float* w_coff  = (const float*)d_in[4];
    const float* b_coff  = (const float*)d_in[5];
    const float* w_dconv = (const float*)d_in[6];
    const float* b_dconv = (const float*)d_in[7];
    float* out = (float*)d_out;

    float* ws = (float*)d_ws;
    float* off_feat = ws;                                   // 8*64*16384   = 8388608 floats
    float* off      = off_feat + (size_t)BB * CC * HWSZ;    // 8*216*16384  = 28311552 floats
    float* wt1      = off + (size_t)BB * C2 * HWSZ;         // 36864
    float* wt2      = wt1 + 64 * 64 * 9;                    // 124416
    float* wtd      = wt2 + 216 * 64 * 9;                   // 36864

    transpose_w_k<<<(64 * 576 + 255) / 256, 256, 0, stream>>>(w_off2d, wt1, 64, 576);
    transpose_w_k<<<(216 * 576 + 255) / 256, 256, 0, stream>>>(w_coff, wt2, 216, 576);
    transpose_w_k<<<(64 * 576 + 255) / 256, 256, 0, stream>>>(w_dconv, wtd, 64, 576);

    dim3 g1(BB * HWSZ / 256, 1);
    conv3x3_k<64><<<g1, 256, 0, stream>>>(cat_fea, wt1, b_off2d, off_feat, 64, 64);
    dim3 g2(BB * HWSZ / 256, 3);
    conv3x3_k<72><<<g2, 256, 0, stream>>>(off_feat, wt2, b_coff, off, 64, 216);
    deform_k<<<BB * HWSZ / 256, 256, 0, stream>>>(f_fea, off, wtd, b_dconv, out);
}

// Round 2
// 1257.726 us; speedup vs baseline: 1.7541x; 1.7541x over previous
//
#include <hip/hip_runtime.h>
#include <math.h>

typedef __attribute__((ext_vector_type(4))) float f32x4;
typedef __attribute__((ext_vector_type(8))) short bf16x8;

#define HH 128
#define WW 128
#define HWSZ 16384
#define BB 8
#define CI 64

__device__ __forceinline__ float bf2f(ushort u) {
    union { uint i; float f; } x; x.i = ((uint)u) << 16; return x.f;
}
__device__ __forceinline__ ushort f2bf(float f) {
    union { float f; uint i; } x; x.f = f;
    uint r = (x.i + 0x7fffu + ((x.i >> 16) & 1u)) >> 16;
    return (ushort)r;
}

// NCHW fp32 (C=64) -> NHWC bf16. grid = B*HW/64 blocks of 256.
__global__ __launch_bounds__(256) void to_nhwc_bf16(const float* __restrict__ x,
                                                    ushort* __restrict__ y) {
    __shared__ ushort lds[64][66];
    int blk = blockIdx.x;
    int b = blk >> 8;
    int hw0 = (blk & 255) << 6;
    int t = threadIdx.x;
    int lane = t & 63;
    int q = t >> 6;
#pragma unroll
    for (int i = 0; i < 16; i++) {
        int c = i * 4 + q;
        float v = x[((size_t)(b * 64 + c) << 14) + hw0 + lane];
        lds[c][lane] = f2bf(v);
    }
    __syncthreads();
#pragma unroll
    for (int i = 0; i < 16; i++) {
        int hwl = i * 4 + q;
        y[((size_t)((b << 14) + hw0 + hwl) << 6) + lane] = lds[lane][hwl];
    }
}

// w[Co][64][3][3] fp32 -> wa[Co_pad][576] bf16 with r = kk*64+ci (zero-padded rows).
__global__ __launch_bounds__(256) void prep_wa(const float* __restrict__ w,
                                               ushort* __restrict__ wa, int Co, int Co_pad) {
    int idx = blockIdx.x * 256 + threadIdx.x;
    if (idx >= Co_pad * 576) return;
    int co = idx / 576, r = idx % 576;
    int kk = r >> 6, ci = r & 63;
    ushort v = 0;
    if (co < Co) v = f2bf(w[(co * 64 + ci) * 9 + kk]);
    wa[idx] = v;
}

// w[O][Ci*9] fp32 -> wt[r][O] fp32 (r = ci*9+k), for deform.
__global__ __launch_bounds__(256) void transpose_w_k(const float* __restrict__ w,
                                                     float* __restrict__ wt, int O, int CiK) {
    int idx = blockIdx.x * 256 + threadIdx.x;
    if (idx >= O * CiK) return;
    int o = idx / CiK, r = idx % CiK;
    wt[r * O + o] = w[idx];
}

// Implicit-GEMM 3x3 conv, bf16 MFMA. Block: 256 thr (4 waves), tile 64co x 64px.
// grid = (co_tiles, B*HW/64). Input/output NHWC bf16 (Cin=64).
// Epilogue: +bias, sigmoid for co >= sigmoid_from, store bf16 NHWC.
__global__ __launch_bounds__(256, 2) void conv_gemm_k(
    const ushort* __restrict__ xt, const ushort* __restrict__ wa,
    const float* __restrict__ bias, ushort* __restrict__ y,
    int Cout, int sigmoid_from) {
    __shared__ ushort Bl[64 * 640];   // row stride 1280 B, XOR-swizzled
    int t = threadIdx.x;
    int cot = blockIdx.x;
    int pt = blockIdx.y;
    int b = pt >> 8;
    int h = (pt >> 1) & 127;
    int w0 = (pt & 1) << 6;

    // ---- build im2col B_lds[px][r], r = kk*64+ci ----
#pragma unroll
    for (int i = 0; i < 18; i++) {
        int id = i * 256 + t;
        int wl = id & 63;
        int u = id >> 6;          // 0..71
        int cg = u / 9;           // ci group 0..7
        int kk = u - cg * 9;      // 0..8
        int hy = h + kk / 3 - 1;
        int wx = w0 + wl + kk % 3 - 1;
        uint4 val = {0u, 0u, 0u, 0u};
        if ((unsigned)hy < (unsigned)HH && (unsigned)wx < (unsigned)WW)
            val = *(const uint4*)(xt + (((size_t)(b << 14) + (hy << 7) + wx) << 6) + cg * 8);
        int kb = kk * 128 + cg * 16;
        kb ^= (wl & 15) << 4;
        *(uint4*)((char*)Bl + wl * 1280 + kb) = val;
    }
    __syncthreads();

    // ---- MFMA main loop ----
    int wv = t >> 6;
    int l = t & 63;
    int lg = l >> 4;
    int lr = l & 15;
    f32x4 acc[4] = {f32x4{0,0,0,0}, f32x4{0,0,0,0}, f32x4{0,0,0,0}, f32x4{0,0,0,0}};
    const ushort* wrow = wa + (size_t)(cot * 64 + wv * 16 + lr) * 576 + lg * 8;
#pragma unroll 2
    for (int c = 0; c < 18; c++) {
        bf16x8 a = *(const bf16x8*)(wrow + c * 32);
        int kb0 = (c * 32 + lg * 8) * 2;
#pragma unroll
        for (int j = 0; j < 4; j++) {
            int px = j * 16 + lr;
            bf16x8 bv = *(const bf16x8*)((char*)Bl + px * 1280 + (kb0 ^ ((px & 15) << 4)));
            acc[j] = __builtin_amdgcn_mfma_f32_16x16x32_bf16(a, bv, acc[j], 0, 0, 0);
        }
    }

    // ---- epilogue: D[co][px], co = cot*64 + wv*16 + lg*4 + r, px = j*16 + lr ----
    int co_g = cot * 64 + wv * 16 + lg * 4;
    if (co_g < Cout) {
        float bs[4];
#pragma unroll
        for (int r = 0; r < 4; r++) bs[r] = bias[co_g + r];
#pragma unroll
        for (int j = 0; j < 4; j++) {
            int pxl = j * 16 + lr;
            size_t pix = (size_t)(b << 14) + (h << 7) + w0 + pxl;
            float v[4];
#pragma unroll
            for (int r = 0; r < 4; r++) {
                float f = acc[j][r] + bs[r];
                if (co_g + r >= sigmoid_from) f = 1.f / (1.f + __expf(-f));
                v[r] = f;
            }
            uint2 st;
            st.x = (uint)f2bf(v[0]) | ((uint)f2bf(v[1]) << 16);
            st.y = (uint)f2bf(v[2]) | ((uint)f2bf(v[3]) << 16);
            *(uint2*)(y + pix * Cout + co_g) = st;
        }
    }
}

// Modulated deformable conv, fp32 accumulate. One thread per px, 32 co per block (y-split).
// xt: f_fea NHWC bf16; off: NHWC bf16 [px][216] (mask channels pre-sigmoided);
// wt: [ci*9+k][64] fp32; out: NCHW fp32.
__global__ __launch_bounds__(256, 2) void deform_k(
    const ushort* __restrict__ xt, const ushort* __restrict__ off,
    const float* __restrict__ wt, const float* __restrict__ bias,
    float* __restrict__ out) {
    int p = blockIdx.x * 256 + threadIdx.x;
    int co0 = blockIdx.y * 32;
    int b = p >> 14;
    int hw = p & 16383;
    int h = hw >> 7;
    int w = hw & 127;
    float acc[32];
#pragma unroll
    for (int o = 0; o < 32; o++) acc[o] = bias[co0 + o];
    const ushort* op = off + (size_t)p * 216;
#pragma unroll 1
    for (int dg = 0; dg < 8; dg++) {
#pragma unroll 1
        for (int k = 0; k < 9; k++) {
            uint dyx = *(const uint*)(op + dg * 18 + 2 * k);
            float dy = bf2f((ushort)(dyx & 0xffff));
            float dx = bf2f((ushort)(dyx >> 16));
            float m = bf2f(op[144 + dg * 9 + k]);
            float py = dy + (float)(h + k / 3 - 1);
            float px = dx + (float)(w + k % 3 - 1);
            float fy = floorf(py), fx = floorf(px);
            int y0 = (int)fy, x0 = (int)fx;
            int y1 = y0 + 1, x1 = x0 + 1;
            float ly = py - fy, lx = px - fx;
            bool vy0 = (unsigned)y0 < (unsigned)HH, vy1 = (unsigned)y1 < (unsigned)HH;
            bool vx0 = (unsigned)x0 < (unsigned)WW, vx1 = (unsigned)x1 < (unsigned)WW;
            float w00 = (vy0 && vx0) ? (1.f - ly) * (1.f - lx) * m : 0.f;
            float w01 = (vy0 && vx1) ? (1.f - ly) * lx * m : 0.f;
            float w10 = (vy1 && vx0) ? ly * (1.f - lx) * m : 0.f;
            float w11 = (vy1 && vx1) ? ly * lx * m : 0.f;
            int y0c = min(max(y0, 0), HH - 1), y1c = min(max(y1, 0), HH - 1);
            int x0c = min(max(x0, 0), WW - 1), x1c = min(max(x1, 0), WW - 1);
            const ushort* c00 = xt + (((size_t)(b << 14) + y0c * WW + x0c) << 6) + dg * 8;
            const ushort* c01 = xt + (((size_t)(b << 14) + y0c * WW + x1c) << 6) + dg * 8;
            const ushort* c10 = xt + (((size_t)(b << 14) + y1c * WW + x0c) << 6) + dg * 8;
            const ushort* c11 = xt + (((size_t)(b << 14) + y1c * WW + x1c) << 6) + dg * 8;
            uint4 q00 = *(const uint4*)c00;
            uint4 q01 = *(const uint4*)c01;
            uint4 q10 = *(const uint4*)c10;
            uint4 q11 = *(const uint4*)c11;
            const ushort* u00 = (const ushort*)&q00;
            const ushort* u01 = (const ushort*)&q01;
            const ushort* u10 = (const ushort*)&q10;
            const ushort* u11 = (const ushort*)&q11;
#pragma unroll
            for (int c = 0; c < 8; c++) {
                float v = w00 * bf2f(u00[c]) + w01 * bf2f(u01[c])
                        + w10 * bf2f(u10[c]) + w11 * bf2f(u11[c]);
                int ch = dg * 8 + c;
                const float* wp = wt + (ch * 9 + k) * 64 + co0;
#pragma unroll
                for (int o = 0; o < 32; o++) acc[o] = fmaf(wp[o], v, acc[o]);
            }
        }
    }
    float* ob = out + ((size_t)(b * 64 + co0) << 14) + hw;
#pragma unroll
    for (int o = 0; o < 32; o++) ob[(size_t)o << 14] = acc[o];
}

extern "C" void kernel_launch(void* const* d_in, const int* in_sizes, int n_in,
                              void* d_out, int out_size, void* d_ws, size_t ws_size,
                              hipStream_t stream) {
    const float* cat_fea = (const float*)d_in[0];
    const float* f_fea   = (const float*)d_in[1];
    const float* w_off2d = (const float*)d_in[2];
    const float* b_off2d = (const float*)d_in[3];
    const float* w_coff  = (const float*)d_in[4];
    const float* b_coff  = (const float*)d_in[5];
    const float* w_dconv = (const float*)d_in[6];
    const float* b_dconv = (const float*)d_in[7];
    float* out = (float*)d_out;

    ushort* x1t      = (ushort*)d_ws;              // 8388608
    ushort* xft      = x1t + 8388608;              // 8388608
    ushort* off_feat = xft + 8388608;              // 8388608
    ushort* off      = off_feat + 8388608;         // 28311552
    ushort* wa1      = off + 28311552;             // 36864
    ushort* wa2      = wa1 + 36864;                // 147456
    float*  wd       = (float*)(wa2 + 147456);     // 36864 floats

    to_nhwc_bf16<<<2048, 256, 0, stream>>>(cat_fea, x1t);
    to_nhwc_bf16<<<2048, 256, 0, stream>>>(f_fea, xft);
    prep_wa<<<(64 * 576 + 255) / 256, 256, 0, stream>>>(w_off2d, wa1, 64, 64);
    prep_wa<<<(256 * 576 + 255) / 256, 256, 0, stream>>>(w_coff, wa2, 216, 256);
    transpose_w_k<<<(64 * 576 + 255) / 256, 256, 0, stream>>>(w_dconv, wd, 64, 576);

    conv_gemm_k<<<dim3(1, 2048), 256, 0, stream>>>(x1t, wa1, b_off2d, off_feat, 64, 1 << 30);
    conv_gemm_k<<<dim3(4, 2048), 256, 0, stream>>>(off_feat, wa2, b_coff, off, 216, 144);
    deform_k<<<dim3(512, 2), 256, 0, stream>>>(xft, off, wd, b_dconv, out);
}

// Round 3
// 360.820 us; speedup vs baseline: 6.1144x; 3.4857x over previous
//
#include <hip/hip_runtime.h>
#include <math.h>

typedef __attribute__((ext_vector_type(4))) float f32x4;
typedef __attribute__((ext_vector_type(8))) short bf16x8;

#define HH 128
#define WW 128
#define HWSZ 16384
#define BB 8
#define CI 64

__device__ __forceinline__ float bf2f(ushort u) {
    union { uint i; float f; } x; x.i = ((uint)u) << 16; return x.f;
}
__device__ __forceinline__ ushort f2bf(float f) {
    union { float f; uint i; } x; x.f = f;
    uint r = (x.i + 0x7fffu + ((x.i >> 16) & 1u)) >> 16;
    return (ushort)r;
}

// NCHW fp32 (C=64) -> NHWC bf16. grid = B*HW/64 blocks of 256.
__global__ __launch_bounds__(256) void to_nhwc_bf16(const float* __restrict__ x,
                                                    ushort* __restrict__ y) {
    __shared__ ushort lds[64][66];
    int blk = blockIdx.x;
    int b = blk >> 8;
    int hw0 = (blk & 255) << 6;
    int t = threadIdx.x;
    int lane = t & 63;
    int q = t >> 6;
#pragma unroll
    for (int i = 0; i < 16; i++) {
        int c = i * 4 + q;
        float v = x[((size_t)(b * 64 + c) << 14) + hw0 + lane];
        lds[c][lane] = f2bf(v);
    }
    __syncthreads();
#pragma unroll
    for (int i = 0; i < 16; i++) {
        int hwl = i * 4 + q;
        y[((size_t)((b << 14) + hw0 + hwl) << 6) + lane] = lds[lane][hwl];
    }
}

// w[Co][64][3][3] fp32 -> wa[Co_pad][576] bf16 with r = kk*64+ci (zero-padded rows).
__global__ __launch_bounds__(256) void prep_wa(const float* __restrict__ w,
                                               ushort* __restrict__ wa, int Co, int Co_pad) {
    int idx = blockIdx.x * 256 + threadIdx.x;
    if (idx >= Co_pad * 576) return;
    int co = idx / 576, r = idx % 576;
    int kk = r >> 6, ci = r & 63;
    ushort v = 0;
    if (co < Co) v = f2bf(w[(co * 64 + ci) * 9 + kk]);
    wa[idx] = v;
}

// Implicit-GEMM 3x3 conv, bf16 MFMA. Block: 256 thr (4 waves), tile 64co x 64px.
// grid = (co_tiles, B*HW/64). Input/output NHWC bf16 (Cin=64).
// Epilogue: +bias, sigmoid for co >= sigmoid_from, store bf16 NHWC.
__global__ __launch_bounds__(256, 2) void conv_gemm_k(
    const ushort* __restrict__ xt, const ushort* __restrict__ wa,
    const float* __restrict__ bias, ushort* __restrict__ y,
    int Cout, int sigmoid_from) {
    __shared__ ushort Bl[64 * 640];   // row stride 1280 B, XOR-swizzled
    int t = threadIdx.x;
    int cot = blockIdx.x;
    int pt = blockIdx.y;
    int b = pt >> 8;
    int h = (pt >> 1) & 127;
    int w0 = (pt & 1) << 6;

    // ---- build im2col B_lds[px][r], r = kk*64+ci ----
#pragma unroll
    for (int i = 0; i < 18; i++) {
        int id = i * 256 + t;
        int wl = id & 63;
        int u = id >> 6;          // 0..71
        int cg = u / 9;           // ci group 0..7
        int kk = u - cg * 9;      // 0..8
        int hy = h + kk / 3 - 1;
        int wx = w0 + wl + kk % 3 - 1;
        uint4 val = {0u, 0u, 0u, 0u};
        if ((unsigned)hy < (unsigned)HH && (unsigned)wx < (unsigned)WW)
            val = *(const uint4*)(xt + (((size_t)(b << 14) + (hy << 7) + wx) << 6) + cg * 8);
        int kb = kk * 128 + cg * 16;
        kb ^= (wl & 15) << 4;
        *(uint4*)((char*)Bl + wl * 1280 + kb) = val;
    }
    __syncthreads();

    // ---- MFMA main loop ----
    int wv = t >> 6;
    int l = t & 63;
    int lg = l >> 4;
    int lr = l & 15;
    f32x4 acc[4] = {f32x4{0,0,0,0}, f32x4{0,0,0,0}, f32x4{0,0,0,0}, f32x4{0,0,0,0}};
    const ushort* wrow = wa + (size_t)(cot * 64 + wv * 16 + lr) * 576 + lg * 8;
#pragma unroll 2
    for (int c = 0; c < 18; c++) {
        bf16x8 a = *(const bf16x8*)(wrow + c * 32);
        int kb0 = (c * 32 + lg * 8) * 2;
#pragma unroll
        for (int j = 0; j < 4; j++) {
            int px = j * 16 + lr;
            bf16x8 bv = *(const bf16x8*)((char*)Bl + px * 1280 + (kb0 ^ ((px & 15) << 4)));
            acc[j] = __builtin_amdgcn_mfma_f32_16x16x32_bf16(a, bv, acc[j], 0, 0, 0);
        }
    }

    // ---- epilogue: D[co][px], co = cot*64 + wv*16 + lg*4 + r, px = j*16 + lr ----
    int co_g = cot * 64 + wv * 16 + lg * 4;
    if (co_g < Cout) {
        float bs[4];
#pragma unroll
        for (int r = 0; r < 4; r++) bs[r] = bias[co_g + r];
#pragma unroll
        for (int j = 0; j < 4; j++) {
            int pxl = j * 16 + lr;
            size_t pix = (size_t)(b << 14) + (h << 7) + w0 + pxl;
            float v[4];
#pragma unroll
            for (int r = 0; r < 4; r++) {
                float f = acc[j][r] + bs[r];
                if (co_g + r >= sigmoid_from) f = 1.f / (1.f + __expf(-f));
                v[r] = f;
            }
            uint2 st;
            st.x = (uint)f2bf(v[0]) | ((uint)f2bf(v[1]) << 16);
            st.y = (uint)f2bf(v[2]) | ((uint)f2bf(v[3]) << 16);
            *(uint2*)(y + pix * Cout + co_g) = st;
        }
    }
}

// Modulated deformable conv as implicit GEMM: phase 1 gathers+bilinear into a
// [64px][576] bf16 vtile in LDS, phase 2 = MFMA 64co x 64px x 576.
// xt: f_fea NHWC bf16; off: NHWC bf16 [px][216] (mask pre-sigmoided);
// wa: [64co][576] bf16 (r = k*64+ci); out: NCHW fp32.
// Grid 2048 blocks, XCD-chunked so each XCD works one batch image (L2-resident x).
__global__ __launch_bounds__(256, 2) void deform_gemm_k(
    const ushort* __restrict__ xt, const ushort* __restrict__ off,
    const ushort* __restrict__ wa, const float* __restrict__ bias,
    float* __restrict__ out) {
    __shared__ ushort Bl[64 * 640];   // vtile, row stride 1280 B, XOR-swizzled
    int t = threadIdx.x;
    int orig = blockIdx.x;
    int blk = (orig & 7) * 256 + (orig >> 3);   // bijective: 2048 = 8 * 256
    int b = blk >> 8;
    int h = (blk >> 1) & 127;
    int w0 = (blk & 1) << 6;
    int lane = t & 63;
    int wv = t >> 6;
    const size_t imgbase = (size_t)b << 14;

    // ---- phase 1: sampling. Wave handles one (dg,k) for px 0..63 per iter. ----
#pragma unroll 2
    for (int i = 0; i < 18; i++) {
        int u = i * 4 + wv;          // 0..71
        int dg = u / 9;
        int k = u - dg * 9;
        int wgl = w0 + lane;
        const ushort* op = off + (imgbase + (h << 7) + wgl) * 216;
        uint dyx = *(const uint*)(op + dg * 18 + 2 * k);
        float dy = bf2f((ushort)(dyx & 0xffff));
        float dx = bf2f((ushort)(dyx >> 16));
        float m = bf2f(op[144 + dg * 9 + k]);
        float py = dy + (float)(h + k / 3 - 1);
        float px_ = dx + (float)(wgl + k % 3 - 1);
        float fy = floorf(py), fx = floorf(px_);
        int y0 = (int)fy, x0 = (int)fx;
        int y1 = y0 + 1, x1 = x0 + 1;
        float ly = py - fy, lx = px_ - fx;
        bool vy0 = (unsigned)y0 < (unsigned)HH, vy1 = (unsigned)y1 < (unsigned)HH;
        bool vx0 = (unsigned)x0 < (unsigned)WW, vx1 = (unsigned)x1 < (unsigned)WW;
        float w00 = (vy0 && vx0) ? (1.f - ly) * (1.f - lx) * m : 0.f;
        float w01 = (vy0 && vx1) ? (1.f - ly) * lx * m : 0.f;
        float w10 = (vy1 && vx0) ? ly * (1.f - lx) * m : 0.f;
        float w11 = (vy1 && vx1) ? ly * lx * m : 0.f;
        int y0c = min(max(y0, 0), HH - 1), y1c = min(max(y1, 0), HH - 1);
        int x0c = min(max(x0, 0), WW - 1), x1c = min(max(x1, 0), WW - 1);
        uint4 q00 = *(const uint4*)(xt + ((imgbase + y0c * WW + x0c) << 6) + dg * 8);
        uint4 q01 = *(const uint4*)(xt + ((imgbase + y0c * WW + x1c) << 6) + dg * 8);
        uint4 q10 = *(const uint4*)(xt + ((imgbase + y1c * WW + x0c) << 6) + dg * 8);
        uint4 q11 = *(const uint4*)(xt + ((imgbase + y1c * WW + x1c) << 6) + dg * 8);
        const ushort* u00 = (const ushort*)&q00;
        const ushort* u01 = (const ushort*)&q01;
        const ushort* u10 = (const ushort*)&q10;
        const ushort* u11 = (const ushort*)&q11;
        uint pk[4];
#pragma unroll
        for (int c2 = 0; c2 < 4; c2++) {
            float v0 = w00 * bf2f(u00[2*c2])   + w01 * bf2f(u01[2*c2])
                     + w10 * bf2f(u10[2*c2])   + w11 * bf2f(u11[2*c2]);
            float v1 = w00 * bf2f(u00[2*c2+1]) + w01 * bf2f(u01[2*c2+1])
                     + w10 * bf2f(u10[2*c2+1]) + w11 * bf2f(u11[2*c2+1]);
            pk[c2] = (uint)f2bf(v0) | ((uint)f2bf(v1) << 16);
        }
        int kb = (k * 128 + dg * 16) ^ ((lane & 15) << 4);
        *(uint4*)((char*)Bl + lane * 1280 + kb) = *(uint4*)pk;
    }
    __syncthreads();

    // ---- phase 2: MFMA (64co x 64px, K=576) ----
    int lg = lane >> 4;
    int lr = lane & 15;
    f32x4 acc[4] = {f32x4{0,0,0,0}, f32x4{0,0,0,0}, f32x4{0,0,0,0}, f32x4{0,0,0,0}};
    const ushort* wrow = wa + (size_t)(wv * 16 + lr) * 576 + lg * 8;
#pragma unroll 2
    for (int c = 0; c < 18; c++) {
        bf16x8 a = *(const bf16x8*)(wrow + c * 32);
        int kb0 = (c * 32 + lg * 8) * 2;
#pragma unroll
        for (int j = 0; j < 4; j++) {
            int px = j * 16 + lr;
            bf16x8 bv = *(const bf16x8*)((char*)Bl + px * 1280 + (kb0 ^ ((px & 15) << 4)));
            acc[j] = __builtin_amdgcn_mfma_f32_16x16x32_bf16(a, bv, acc[j], 0, 0, 0);
        }
    }

    // ---- epilogue: out NCHW fp32. D[co][px]: co = wv*16+lg*4+r, px = j*16+lr ----
    int co_g = wv * 16 + lg * 4;
    float bs[4];
#pragma unroll
    for (int r = 0; r < 4; r++) bs[r] = bias[co_g + r];
#pragma unroll
    for (int j = 0; j < 4; j++) {
        int pxl = j * 16 + lr;
        int hw = (h << 7) + w0 + pxl;
#pragma unroll
        for (int r = 0; r < 4; r++) {
            out[((size_t)(b * 64 + co_g + r) << 14) + hw] = acc[j][r] + bs[r];
        }
    }
}

extern "C" void kernel_launch(void* const* d_in, const int* in_sizes, int n_in,
                              void* d_out, int out_size, void* d_ws, size_t ws_size,
                              hipStream_t stream) {
    const float* cat_fea = (const float*)d_in[0];
    const float* f_fea   = (const float*)d_in[1];
    const float* w_off2d = (const float*)d_in[2];
    const float* b_off2d = (const float*)d_in[3];
    const float* w_coff  = (const float*)d_in[4];
    const float* b_coff  = (const float*)d_in[5];
    const float* w_dconv = (const float*)d_in[6];
    const float* b_dconv = (const float*)d_in[7];
    float* out = (float*)d_out;

    ushort* x1t      = (ushort*)d_ws;              // 8388608
    ushort* xft      = x1t + 8388608;              // 8388608
    ushort* off_feat = xft + 8388608;              // 8388608
    ushort* off      = off_feat + 8388608;         // 28311552
    ushort* wa1      = off + 28311552;             // 36864
    ushort* wa2      = wa1 + 36864;                // 147456
    ushort* wad      = wa2 + 147456;               // 36864

    to_nhwc_bf16<<<2048, 256, 0, stream>>>(cat_fea, x1t);
    to_nhwc_bf16<<<2048, 256, 0, stream>>>(f_fea, xft);
    prep_wa<<<(64 * 576 + 255) / 256, 256, 0, stream>>>(w_off2d, wa1, 64, 64);
    prep_wa<<<(256 * 576 + 255) / 256, 256, 0, stream>>>(w_coff, wa2, 216, 256);
    prep_wa<<<(64 * 576 + 255) / 256, 256, 0, stream>>>(w_dconv, wad, 64, 64);

    conv_gemm_k<<<dim3(1, 2048), 256, 0, stream>>>(x1t, wa1, b_off2d, off_feat, 64, 1 << 30);
    conv_gemm_k<<<dim3(4, 2048), 256, 0, stream>>>(off_feat, wa2, b_coff, off, 216, 144);
    deform_gemm_k<<<2048, 256, 0, stream>>>(xft, off, wad, b_dconv, out);
}

// Round 4
// 306.438 us; speedup vs baseline: 7.1995x; 1.1775x over previous
//
#include <hip/hip_runtime.h>
#include <math.h>

typedef __attribute__((ext_vector_type(4))) float f32x4;
typedef __attribute__((ext_vector_type(8))) short bf16x8;

#define HH 128
#define WW 128
#define HWSZ 16384
#define BB 8
#define CI 64

__device__ __forceinline__ float bf2f(ushort u) {
    union { uint i; float f; } x; x.i = ((uint)u) << 16; return x.f;
}
__device__ __forceinline__ ushort f2bf(float f) {
    union { float f; uint i; } x; x.f = f;
    uint r = (x.i + 0x7fffu + ((x.i >> 16) & 1u)) >> 16;
    return (ushort)r;
}

// NCHW fp32 (C=64) -> NHWC bf16. grid = B*HW/64 blocks of 256.
__global__ __launch_bounds__(256) void to_nhwc_bf16(const float* __restrict__ x,
                                                    ushort* __restrict__ y) {
    __shared__ ushort lds[64][66];
    int blk = blockIdx.x;
    int b = blk >> 8;
    int hw0 = (blk & 255) << 6;
    int t = threadIdx.x;
    int lane = t & 63;
    int q = t >> 6;
#pragma unroll
    for (int i = 0; i < 16; i++) {
        int c = i * 4 + q;
        float v = x[((size_t)(b * 64 + c) << 14) + hw0 + lane];
        lds[c][lane] = f2bf(v);
    }
    __syncthreads();
#pragma unroll
    for (int i = 0; i < 16; i++) {
        int hwl = i * 4 + q;
        y[((size_t)((b << 14) + hw0 + hwl) << 6) + lane] = lds[lane][hwl];
    }
}

// w[Co][64][3][3] fp32 -> wa[Co_pad][576] bf16 with r = kk*64+ci (zero-padded rows).
__global__ __launch_bounds__(256) void prep_wa(const float* __restrict__ w,
                                               ushort* __restrict__ wa, int Co, int Co_pad) {
    int idx = blockIdx.x * 256 + threadIdx.x;
    if (idx >= Co_pad * 576) return;
    int co = idx / 576, r = idx % 576;
    int kk = r >> 6, ci = r & 63;
    ushort v = 0;
    if (co < Co) v = f2bf(w[(co * 64 + ci) * 9 + kk]);
    wa[idx] = v;
}

// ---------------------------------------------------------------------------
// K-chunked, double-buffered implicit-GEMM 3x3 conv (bf16 MFMA).
// Block = 256 thr (4 waves), tile = 64 px x (NCO*64 co). K = 576 in 3 chunks
// of 192 (chunk ch = filter row ch, input row h+ch-1). LDS 2 x 24576 B.
// Grid = 2048 (XCD-chunked: each XCD gets one image). NHWC bf16 in/out.
// ---------------------------------------------------------------------------
template<int NCO>
__global__ __launch_bounds__(256, 3) void conv_pipe_k(
    const ushort* __restrict__ xt, const ushort* __restrict__ wa,
    const float* __restrict__ bias, ushort* __restrict__ y,
    int Cout, int sigmoid_from) {
    __shared__ ushort Bl[2 * 64 * 192];   // 2 buffers, row stride 384 B, XOR-swizzled
    int t = threadIdx.x;
    int orig = blockIdx.x;
    int blk = (orig & 7) * 256 + (orig >> 3);   // bijective, 2048 = 8*256; XCD = image
    int b = blk >> 8;
    int h = (blk >> 1) & 127;
    int w0 = (blk & 1) << 6;
    int lane = t & 63;
    int wv = t >> 6;
    int lg = lane >> 4;
    int lr = lane & 15;
    const size_t imgbase = (size_t)b << 14;

    uint4 st[6];

#define STAGE_LOAD(CH) do {                                                     \
    int hy = h + (CH) - 1;                                                      \
    bool vr = (unsigned)hy < (unsigned)HH;                                      \
    _Pragma("unroll")                                                           \
    for (int i = 0; i < 6; i++) {                                               \
        int u = i * 4 + wv;                                                     \
        int cg = u / 3;                                                         \
        int q = u - cg * 3;                                                     \
        int wx = w0 + lane + q - 1;                                             \
        uint4 v = {0u, 0u, 0u, 0u};                                             \
        if (vr && (unsigned)wx < (unsigned)WW)                                  \
            v = *(const uint4*)(xt + ((imgbase + (hy << 7) + wx) << 6) + cg * 8);\
        st[i] = v;                                                              \
    } } while (0)

#define STAGE_WRITE(BI) do {                                                    \
    _Pragma("unroll")                                                           \
    for (int i = 0; i < 6; i++) {                                               \
        int u = i * 4 + wv;                                                     \
        int cg = u / 3;                                                         \
        int q = u - cg * 3;                                                     \
        int kb = (q * 128 + cg * 16) ^ ((lane & 7) << 4);                       \
        *(uint4*)((char*)Bl + (BI) * 24576 + lane * 384 + kb) = st[i];          \
    } } while (0)

    f32x4 acc[NCO][4];
#pragma unroll
    for (int n = 0; n < NCO; n++)
#pragma unroll
        for (int j = 0; j < 4; j++) acc[n][j] = f32x4{0, 0, 0, 0};

#define MFMA_CHUNK(CH, BI) do {                                                 \
    _Pragma("unroll")                                                           \
    for (int c = 0; c < 6; c++) {                                               \
        bf16x8 bv[4];                                                           \
        _Pragma("unroll")                                                       \
        for (int j = 0; j < 4; j++) {                                           \
            int px = j * 16 + lr;                                               \
            int kb = (c * 64 + lg * 16) ^ ((px & 7) << 4);                      \
            bv[j] = *(const bf16x8*)((char*)Bl + (BI) * 24576 + px * 384 + kb); \
        }                                                                       \
        _Pragma("unroll")                                                       \
        for (int n = 0; n < NCO; n++) {                                         \
            bf16x8 a = *(const bf16x8*)(wa +                                    \
                (size_t)(n * 64 + wv * 16 + lr) * 576 + (CH) * 192 + c * 32 + lg * 8); \
            _Pragma("unroll")                                                   \
            for (int j = 0; j < 4; j++)                                         \
                acc[n][j] = __builtin_amdgcn_mfma_f32_16x16x32_bf16(a, bv[j], acc[n][j], 0, 0, 0); \
        }                                                                       \
    } } while (0)

    STAGE_LOAD(0);
    STAGE_WRITE(0);
    __syncthreads();

    STAGE_LOAD(1);
    MFMA_CHUNK(0, 0);
    __syncthreads();
    STAGE_WRITE(1);
    __syncthreads();

    STAGE_LOAD(2);
    MFMA_CHUNK(1, 1);
    __syncthreads();
    STAGE_WRITE(0);
    __syncthreads();

    MFMA_CHUNK(2, 0);

    // ---- epilogue: D[co][px], co = n*64 + wv*16 + lg*4 + r, px = j*16 + lr ----
#pragma unroll
    for (int n = 0; n < NCO; n++) {
        int co_g = n * 64 + wv * 16 + lg * 4;
        if (co_g < Cout) {
            float bs[4];
#pragma unroll
            for (int r = 0; r < 4; r++) bs[r] = bias[co_g + r];
#pragma unroll
            for (int j = 0; j < 4; j++) {
                int pxl = j * 16 + lr;
                size_t pix = imgbase + (h << 7) + w0 + pxl;
                float v[4];
#pragma unroll
                for (int r = 0; r < 4; r++) {
                    float f = acc[n][j][r] + bs[r];
                    if (co_g + r >= sigmoid_from) f = 1.f / (1.f + __expf(-f));
                    v[r] = f;
                }
                uint2 s2;
                s2.x = (uint)f2bf(v[0]) | ((uint)f2bf(v[1]) << 16);
                s2.y = (uint)f2bf(v[2]) | ((uint)f2bf(v[3]) << 16);
                *(uint2*)(y + pix * Cout + co_g) = s2;
            }
        }
    }
#undef STAGE_LOAD
#undef STAGE_WRITE
#undef MFMA_CHUNK
}

// Modulated deformable conv as implicit GEMM: phase 1 gathers+bilinear into a
// [64px][576] bf16 vtile in LDS, phase 2 = MFMA 64co x 64px x 576.
__global__ __launch_bounds__(256, 2) void deform_gemm_k(
    const ushort* __restrict__ xt, const ushort* __restrict__ off,
    const ushort* __restrict__ wa, const float* __restrict__ bias,
    float* __restrict__ out) {
    __shared__ ushort Bl[64 * 640];   // vtile, row stride 1280 B, XOR-swizzled
    int t = threadIdx.x;
    int orig = blockIdx.x;
    int blk = (orig & 7) * 256 + (orig >> 3);   // bijective: 2048 = 8 * 256
    int b = blk >> 8;
    int h = (blk >> 1) & 127;
    int w0 = (blk & 1) << 6;
    int lane = t & 63;
    int wv = t >> 6;
    const size_t imgbase = (size_t)b << 14;

    // ---- phase 1: sampling. Wave handles one (dg,k) for px 0..63 per iter. ----
#pragma unroll 2
    for (int i = 0; i < 18; i++) {
        int u = i * 4 + wv;          // 0..71
        int dg = u / 9;
        int k = u - dg * 9;
        int wgl = w0 + lane;
        const ushort* op = off + (imgbase + (h << 7) + wgl) * 216;
        uint dyx = *(const uint*)(op + dg * 18 + 2 * k);
        float dy = bf2f((ushort)(dyx & 0xffff));
        float dx = bf2f((ushort)(dyx >> 16));
        float m = bf2f(op[144 + dg * 9 + k]);
        float py = dy + (float)(h + k / 3 - 1);
        float px_ = dx + (float)(wgl + k % 3 - 1);
        float fy = floorf(py), fx = floorf(px_);
        int y0 = (int)fy, x0 = (int)fx;
        int y1 = y0 + 1, x1 = x0 + 1;
        float ly = py - fy, lx = px_ - fx;
        bool vy0 = (unsigned)y0 < (unsigned)HH, vy1 = (unsigned)y1 < (unsigned)HH;
        bool vx0 = (unsigned)x0 < (unsigned)WW, vx1 = (unsigned)x1 < (unsigned)WW;
        float w00 = (vy0 && vx0) ? (1.f - ly) * (1.f - lx) * m : 0.f;
        float w01 = (vy0 && vx1) ? (1.f - ly) * lx * m : 0.f;
        float w10 = (vy1 && vx0) ? ly * (1.f - lx) * m : 0.f;
        float w11 = (vy1 && vx1) ? ly * lx * m : 0.f;
        int y0c = min(max(y0, 0), HH - 1), y1c = min(max(y1, 0), HH - 1);
        int x0c = min(max(x0, 0), WW - 1), x1c = min(max(x1, 0), WW - 1);
        uint4 q00 = *(const uint4*)(xt + ((imgbase + y0c * WW + x0c) << 6) + dg * 8);
        uint4 q01 = *(const uint4*)(xt + ((imgbase + y0c * WW + x1c) << 6) + dg * 8);
        uint4 q10 = *(const uint4*)(xt + ((imgbase + y1c * WW + x0c) << 6) + dg * 8);
        uint4 q11 = *(const uint4*)(xt + ((imgbase + y1c * WW + x1c) << 6) + dg * 8);
        const ushort* u00 = (const ushort*)&q00;
        const ushort* u01 = (const ushort*)&q01;
        const ushort* u10 = (const ushort*)&q10;
        const ushort* u11 = (const ushort*)&q11;
        uint pk[4];
#pragma unroll
        for (int c2 = 0; c2 < 4; c2++) {
            float v0 = w00 * bf2f(u00[2*c2])   + w01 * bf2f(u01[2*c2])
                     + w10 * bf2f(u10[2*c2])   + w11 * bf2f(u11[2*c2]);
            float v1 = w00 * bf2f(u00[2*c2+1]) + w01 * bf2f(u01[2*c2+1])
                     + w10 * bf2f(u10[2*c2+1]) + w11 * bf2f(u11[2*c2+1]);
            pk[c2] = (uint)f2bf(v0) | ((uint)f2bf(v1) << 16);
        }
        int kb = (k * 128 + dg * 16) ^ ((lane & 15) << 4);
        *(uint4*)((char*)Bl + lane * 1280 + kb) = *(uint4*)pk;
    }
    __syncthreads();

    // ---- phase 2: MFMA (64co x 64px, K=576) ----
    int lg = lane >> 4;
    int lr = lane & 15;
    f32x4 acc[4] = {f32x4{0,0,0,0}, f32x4{0,0,0,0}, f32x4{0,0,0,0}, f32x4{0,0,0,0}};
    const ushort* wrow = wa + (size_t)(wv * 16 + lr) * 576 + lg * 8;
#pragma unroll 2
    for (int c = 0; c < 18; c++) {
        bf16x8 a = *(const bf16x8*)(wrow + c * 32);
        int kb0 = (c * 32 + lg * 8) * 2;
#pragma unroll
        for (int j = 0; j < 4; j++) {
            int px = j * 16 + lr;
            bf16x8 bv = *(const bf16x8*)((char*)Bl + px * 1280 + (kb0 ^ ((px & 15) << 4)));
            acc[j] = __builtin_amdgcn_mfma_f32_16x16x32_bf16(a, bv, acc[j], 0, 0, 0);
        }
    }

    // ---- epilogue: out NCHW fp32. D[co][px]: co = wv*16+lg*4+r, px = j*16+lr ----
    int co_g = wv * 16 + lg * 4;
    float bs[4];
#pragma unroll
    for (int r = 0; r < 4; r++) bs[r] = bias[co_g + r];
#pragma unroll
    for (int j = 0; j < 4; j++) {
        int pxl = j * 16 + lr;
        int hw = (h << 7) + w0 + pxl;
#pragma unroll
        for (int r = 0; r < 4; r++) {
            out[((size_t)(b * 64 + co_g + r) << 14) + hw] = acc[j][r] + bs[r];
        }
    }
}

extern "C" void kernel_launch(void* const* d_in, const int* in_sizes, int n_in,
                              void* d_out, int out_size, void* d_ws, size_t ws_size,
                              hipStream_t stream) {
    const float* cat_fea = (const float*)d_in[0];
    const float* f_fea   = (const float*)d_in[1];
    const float* w_off2d = (const float*)d_in[2];
    const float* b_off2d = (const float*)d_in[3];
    const float* w_coff  = (const float*)d_in[4];
    const float* b_coff  = (const float*)d_in[5];
    const float* w_dconv = (const float*)d_in[6];
    const float* b_dconv = (const float*)d_in[7];
    float* out = (float*)d_out;

    ushort* x1t      = (ushort*)d_ws;              // 8388608
    ushort* xft      = x1t + 8388608;              // 8388608
    ushort* off_feat = xft + 8388608;              // 8388608
    ushort* off      = off_feat + 8388608;         // 28311552
    ushort* wa1      = off + 28311552;             // 36864
    ushort* wa2      = wa1 + 36864;                // 147456
    ushort* wad      = wa2 + 147456;               // 36864

    to_nhwc_bf16<<<2048, 256, 0, stream>>>(cat_fea, x1t);
    to_nhwc_bf16<<<2048, 256, 0, stream>>>(f_fea, xft);
    prep_wa<<<(64 * 576 + 255) / 256, 256, 0, stream>>>(w_off2d, wa1, 64, 64);
    prep_wa<<<(256 * 576 + 255) / 256, 256, 0, stream>>>(w_coff, wa2, 216, 256);
    prep_wa<<<(64 * 576 + 255) / 256, 256, 0, stream>>>(w_dconv, wad, 64, 64);

    conv_pipe_k<1><<<2048, 256, 0, stream>>>(x1t, wa1, b_off2d, off_feat, 64, 1 << 30);
    conv_pipe_k<4><<<2048, 256, 0, stream>>>(off_feat, wa2, b_coff, off, 216, 144);
    deform_gemm_k<<<2048, 256, 0, stream>>>(xft, off, wad, b_dconv, out);
}

// Round 5
// 211.290 us; speedup vs baseline: 10.4415x; 1.4503x over previous
//
#include <hip/hip_runtime.h>
#include <math.h>

typedef __attribute__((ext_vector_type(4))) float f32x4;
typedef __attribute__((ext_vector_type(8))) short bf16x8;

#define HH 128
#define WW 128
#define HWSZ 16384
#define BHW 131072
#define BB 8

__device__ __forceinline__ float bf2f(ushort u) {
    union { uint i; float f; } x; x.i = ((uint)u) << 16; return x.f;
}
__device__ __forceinline__ ushort f2bf(float f) {
    union { float f; uint i; } x; x.f = f;
    uint r = (x.i + 0x7fffu + ((x.i >> 16) & 1u)) >> 16;
    return (ushort)r;
}

// NCHW fp32 (C=64) -> group-planar bf16 xg[b][cg][hw][8].
__global__ __launch_bounds__(256) void to_gp_bf16(const float* __restrict__ x,
                                                  ushort* __restrict__ y) {
    __shared__ ushort lds[64][66];
    int blk = blockIdx.x;
    int b = blk >> 8;
    int hw0 = (blk & 255) << 6;
    int t = threadIdx.x;
    int lane = t & 63;
    int q = t >> 6;
#pragma unroll
    for (int i = 0; i < 16; i++) {
        int c = i * 4 + q;
        lds[c][lane] = f2bf(x[((size_t)(b * 64 + c) << 14) + hw0 + lane]);
    }
    __syncthreads();
#pragma unroll
    for (int it = 0; it < 2; it++) {
        int id = it * 256 + t;
        int cg = id >> 6;
        int px = id & 63;
        uint pk[4];
#pragma unroll
        for (int j = 0; j < 4; j++)
            pk[j] = (uint)lds[cg * 8 + 2 * j][px] | ((uint)lds[cg * 8 + 2 * j + 1][px] << 16);
        *(uint4*)(y + ((((size_t)b * 8 + cg) << 14) + hw0 + px) * 8) = *(uint4*)pk;
    }
}

// w[Co][64][3][3] fp32 -> wa[Co_pad][576] bf16 with r = kk*64+ci (zero-padded rows).
__global__ __launch_bounds__(256) void prep_wa(const float* __restrict__ w,
                                               ushort* __restrict__ wa, int Co, int Co_pad) {
    int idx = blockIdx.x * 256 + threadIdx.x;
    if (idx >= Co_pad * 576) return;
    int co = idx / 576, r = idx % 576;
    int kk = r >> 6, ci = r & 63;
    ushort v = 0;
    if (co < Co) v = f2bf(w[(co * 64 + ci) * 9 + kk]);
    wa[idx] = v;
}

// ---------------------------------------------------------------------------
// K-chunked double-buffered implicit-GEMM 3x3 conv (bf16 MFMA).
// Input: group-planar bf16 xg[b][cg][hw][8]. MODE 0: output group-planar bf16.
// MODE 1: output planar dyx (uint pair) + pre-sigmoided mask planes.
// ---------------------------------------------------------------------------
template<int NCO, int MODE>
__global__ __launch_bounds__(256, 3) void conv_pipe_k(
    const ushort* __restrict__ xt, const ushort* __restrict__ wa,
    const float* __restrict__ bias, ushort* __restrict__ y,
    uint* __restrict__ dyxp, ushort* __restrict__ mpl, int Cout) {
    __shared__ ushort Bl[2 * 64 * 192];   // 2 buffers, row stride 384 B, XOR-swizzled
    int t = threadIdx.x;
    int orig = blockIdx.x;
    int blk = (orig & 7) * 256 + (orig >> 3);   // bijective, 2048 = 8*256; XCD = image
    int b = blk >> 8;
    int h = (blk >> 1) & 127;
    int w0 = (blk & 1) << 6;
    int lane = t & 63;
    int wv = t >> 6;
    int lg = lane >> 4;
    int lr = lane & 15;

    uint4 st[6];

#define STAGE_LOAD(CH) do {                                                     \
    int hy = h + (CH) - 1;                                                      \
    bool vr = (unsigned)hy < (unsigned)HH;                                      \
    _Pragma("unroll")                                                           \
    for (int i = 0; i < 6; i++) {                                               \
        int u = i * 4 + wv;                                                     \
        int cg = u / 3;                                                         \
        int q = u - cg * 3;                                                     \
        int wx = w0 + lane + q - 1;                                             \
        uint4 v = {0u, 0u, 0u, 0u};                                             \
        if (vr && (unsigned)wx < (unsigned)WW)                                  \
            v = *(const uint4*)(xt + ((((size_t)b * 8 + cg) << 14) + (hy << 7) + wx) * 8); \
        st[i] = v;                                                              \
    } } while (0)

#define STAGE_WRITE(BI) do {                                                    \
    _Pragma("unroll")                                                           \
    for (int i = 0; i < 6; i++) {                                               \
        int u = i * 4 + wv;                                                     \
        int cg = u / 3;                                                         \
        int q = u - cg * 3;                                                     \
        int kb = (q * 128 + cg * 16) ^ ((lane & 7) << 4);                       \
        *(uint4*)((char*)Bl + (BI) * 24576 + lane * 384 + kb) = st[i];          \
    } } while (0)

    f32x4 acc[NCO][4];
#pragma unroll
    for (int n = 0; n < NCO; n++)
#pragma unroll
        for (int j = 0; j < 4; j++) acc[n][j] = f32x4{0, 0, 0, 0};

#define MFMA_CHUNK(CH, BI) do {                                                 \
    _Pragma("unroll")                                                           \
    for (int c = 0; c < 6; c++) {                                               \
        bf16x8 bv[4];                                                           \
        _Pragma("unroll")                                                       \
        for (int j = 0; j < 4; j++) {                                           \
            int px = j * 16 + lr;                                               \
            int kb = (c * 64 + lg * 16) ^ ((px & 7) << 4);                      \
            bv[j] = *(const bf16x8*)((char*)Bl + (BI) * 24576 + px * 384 + kb); \
        }                                                                       \
        _Pragma("unroll")                                                       \
        for (int n = 0; n < NCO; n++) {                                         \
            bf16x8 a = *(const bf16x8*)(wa +                                    \
                (size_t)(n * 64 + wv * 16 + lr) * 576 + (CH) * 192 + c * 32 + lg * 8); \
            _Pragma("unroll")                                                   \
            for (int j = 0; j < 4; j++)                                         \
                acc[n][j] = __builtin_amdgcn_mfma_f32_16x16x32_bf16(a, bv[j], acc[n][j], 0, 0, 0); \
        }                                                                       \
    } } while (0)

    STAGE_LOAD(0);
    STAGE_WRITE(0);
    __syncthreads();

    STAGE_LOAD(1);
    MFMA_CHUNK(0, 0);
    __syncthreads();
    STAGE_WRITE(1);
    __syncthreads();

    STAGE_LOAD(2);
    MFMA_CHUNK(1, 1);
    __syncthreads();
    STAGE_WRITE(0);
    __syncthreads();

    MFMA_CHUNK(2, 0);

    // ---- epilogue: D[co][px], co = n*64 + wv*16 + lg*4 + r, px = j*16 + lr ----
#pragma unroll
    for (int n = 0; n < NCO; n++) {
        int co_g = n * 64 + wv * 16 + lg * 4;
        if (co_g < Cout) {
            float bs[4];
#pragma unroll
            for (int r = 0; r < 4; r++) bs[r] = bias[co_g + r];
#pragma unroll
            for (int j = 0; j < 4; j++) {
                int pxl = j * 16 + lr;
                int hw = (h << 7) + w0 + pxl;
                int bhw = (b << 14) + hw;
                if (MODE == 0) {
                    int cg = co_g >> 3, cs = co_g & 7;
                    uint2 s2;
                    s2.x = (uint)f2bf(acc[n][j][0] + bs[0]) | ((uint)f2bf(acc[n][j][1] + bs[1]) << 16);
                    s2.y = (uint)f2bf(acc[n][j][2] + bs[2]) | ((uint)f2bf(acc[n][j][3] + bs[3]) << 16);
                    *(uint2*)(y + ((((size_t)b * 8 + cg) << 14) + hw) * 8 + cs) = s2;
                } else if (co_g < 144) {
                    int p0 = co_g >> 1;
                    uint u0 = (uint)f2bf(acc[n][j][0] + bs[0]) | ((uint)f2bf(acc[n][j][1] + bs[1]) << 16);
                    uint u1 = (uint)f2bf(acc[n][j][2] + bs[2]) | ((uint)f2bf(acc[n][j][3] + bs[3]) << 16);
                    dyxp[(size_t)p0 * BHW + bhw] = u0;
                    dyxp[(size_t)(p0 + 1) * BHW + bhw] = u1;
                } else {
#pragma unroll
                    for (int r = 0; r < 4; r++) {
                        float f = 1.f / (1.f + __expf(-(acc[n][j][r] + bs[r])));
                        mpl[(size_t)(co_g - 144 + r) * BHW + bhw] = f2bf(f);
                    }
                }
            }
        }
    }
#undef STAGE_LOAD
#undef STAGE_WRITE
#undef MFMA_CHUNK
}

// ---------------------------------------------------------------------------
// Modulated deformable conv, K-chunked double-buffered pipeline.
// xg: f_fea group-planar bf16; dyxp/mpl: planar offsets (coalesced reads);
// wa: [64co][576] bf16 (r = k*64+ci); out: NCHW fp32.
// ---------------------------------------------------------------------------
__global__ __launch_bounds__(256, 3) void deform_pipe_k(
    const ushort* __restrict__ xg, const uint* __restrict__ dyxp,
    const ushort* __restrict__ mpl, const ushort* __restrict__ wa,
    const float* __restrict__ bias, float* __restrict__ out) {
    __shared__ ushort Bl[2 * 64 * 192];
    int t = threadIdx.x;
    int orig = blockIdx.x;
    int blk = (orig & 7) * 256 + (orig >> 3);   // bijective: 2048 = 8 * 256
    int b = blk >> 8;
    int h = (blk >> 1) & 127;
    int w0 = (blk & 1) << 6;
    int lane = t & 63;
    int wv = t >> 6;
    int lg = lane >> 4;
    int lr = lane & 15;
    int wgl = w0 + lane;
    int bhw = (b << 14) + (h << 7) + wgl;

    uint4 st[6];

#define SAMPLE(KR) do {                                                         \
    _Pragma("unroll")                                                           \
    for (int i = 0; i < 6; i++) {                                               \
        int u = i * 4 + wv;                                                     \
        int dg = u / 3;                                                         \
        int q = u - dg * 3;                                                     \
        int p = dg * 9 + (KR) * 3 + q;                                          \
        uint dyx = dyxp[(size_t)p * BHW + bhw];                                 \
        float m = bf2f(mpl[(size_t)p * BHW + bhw]);                             \
        float dy = bf2f((ushort)(dyx & 0xffff));                                \
        float dx = bf2f((ushort)(dyx >> 16));                                   \
        float py = dy + (float)(h + (KR) - 1);                                  \
        float px_ = dx + (float)(wgl + q - 1);                                  \
        float fy = floorf(py), fx = floorf(px_);                                \
        int y0 = (int)fy, x0 = (int)fx;                                         \
        int y1 = y0 + 1, x1 = x0 + 1;                                           \
        float ly = py - fy, lx = px_ - fx;                                      \
        bool vy0 = (unsigned)y0 < (unsigned)HH, vy1 = (unsigned)y1 < (unsigned)HH; \
        bool vx0 = (unsigned)x0 < (unsigned)WW, vx1 = (unsigned)x1 < (unsigned)WW; \
        float w00 = (vy0 && vx0) ? (1.f - ly) * (1.f - lx) * m : 0.f;           \
        float w01 = (vy0 && vx1) ? (1.f - ly) * lx * m : 0.f;                   \
        float w10 = (vy1 && vx0) ? ly * (1.f - lx) * m : 0.f;                   \
        float w11 = (vy1 && vx1) ? ly * lx * m : 0.f;                           \
        int y0c = min(max(y0, 0), HH - 1), y1c = min(max(y1, 0), HH - 1);       \
        int x0c = min(max(x0, 0), WW - 1), x1c = min(max(x1, 0), WW - 1);       \
        const ushort* gb = xg + (((size_t)b * 8 + dg) << 17);                   \
        uint4 q00 = *(const uint4*)(gb + ((y0c << 7) + x0c) * 8);               \
        uint4 q01 = *(const uint4*)(gb + ((y0c << 7) + x1c) * 8);               \
        uint4 q10 = *(const uint4*)(gb + ((y1c << 7) + x0c) * 8);               \
        uint4 q11 = *(const uint4*)(gb + ((y1c << 7) + x1c) * 8);               \
        const ushort* u00 = (const ushort*)&q00;                                \
        const ushort* u01 = (const ushort*)&q01;                                \
        const ushort* u10 = (const ushort*)&q10;                                \
        const ushort* u11 = (const ushort*)&q11;                                \
        uint pk[4];                                                             \
        _Pragma("unroll")                                                       \
        for (int c2 = 0; c2 < 4; c2++) {                                        \
            float v0 = w00 * bf2f(u00[2*c2])   + w01 * bf2f(u01[2*c2])          \
                     + w10 * bf2f(u10[2*c2])   + w11 * bf2f(u11[2*c2]);         \
            float v1 = w00 * bf2f(u00[2*c2+1]) + w01 * bf2f(u01[2*c2+1])        \
                     + w10 * bf2f(u10[2*c2+1]) + w11 * bf2f(u11[2*c2+1]);       \
            pk[c2] = (uint)f2bf(v0) | ((uint)f2bf(v1) << 16);                   \
        }                                                                       \
        st[i] = *(uint4*)pk;                                                    \
    } } while (0)

#define STAGE_WRITE(BI) do {                                                    \
    _Pragma("unroll")                                                           \
    for (int i = 0; i < 6; i++) {                                               \
        int u = i * 4 + wv;                                                     \
        int dg = u / 3;                                                         \
        int q = u - dg * 3;                                                     \
        int kb = (q * 128 + dg * 16) ^ ((lane & 7) << 4);                       \
        *(uint4*)((char*)Bl + (BI) * 24576 + lane * 384 + kb) = st[i];          \
    } } while (0)

    f32x4 acc[4] = {f32x4{0,0,0,0}, f32x4{0,0,0,0}, f32x4{0,0,0,0}, f32x4{0,0,0,0}};

#define MFMA_CHUNK(CH, BI) do {                                                 \
    _Pragma("unroll")                                                           \
    for (int c = 0; c < 6; c++) {                                               \
        bf16x8 a = *(const bf16x8*)(wa +                                        \
            (size_t)(wv * 16 + lr) * 576 + (CH) * 192 + c * 32 + lg * 8);       \
        _Pragma("unroll")                                                       \
        for (int j = 0; j < 4; j++) {                                           \
            int px = j * 16 + lr;                                               \
            int kb = (c * 64 + lg * 16) ^ ((px & 7) << 4);                      \
            bf16x8 bv = *(const bf16x8*)((char*)Bl + (BI) * 24576 + px * 384 + kb); \
            acc[j] = __builtin_amdgcn_mfma_f32_16x16x32_bf16(a, bv, acc[j], 0, 0, 0); \
        }                                                                       \
    } } while (0)

    SAMPLE(0);
    STAGE_WRITE(0);
    __syncthreads();

    SAMPLE(1);
    MFMA_CHUNK(0, 0);
    __syncthreads();
    STAGE_WRITE(1);
    __syncthreads();

    SAMPLE(2);
    MFMA_CHUNK(1, 1);
    __syncthreads();
    STAGE_WRITE(0);
    __syncthreads();

    MFMA_CHUNK(2, 0);

    // ---- epilogue: out NCHW fp32. D[co][px]: co = wv*16+lg*4+r, px = j*16+lr ----
    int co_g = wv * 16 + lg * 4;
    float bs[4];
#pragma unroll
    for (int r = 0; r < 4; r++) bs[r] = bias[co_g + r];
#pragma unroll
    for (int j = 0; j < 4; j++) {
        int pxl = j * 16 + lr;
        int hw = (h << 7) + w0 + pxl;
#pragma unroll
        for (int r = 0; r < 4; r++) {
            out[((size_t)(b * 64 + co_g + r) << 14) + hw] = acc[j][r] + bs[r];
        }
    }
#undef SAMPLE
#undef STAGE_WRITE
#undef MFMA_CHUNK
}

extern "C" void kernel_launch(void* const* d_in, const int* in_sizes, int n_in,
                              void* d_out, int out_size, void* d_ws, size_t ws_size,
                              hipStream_t stream) {
    const float* cat_fea = (const float*)d_in[0];
    const float* f_fea   = (const float*)d_in[1];
    const float* w_off2d = (const float*)d_in[2];
    const float* b_off2d = (const float*)d_in[3];
    const float* w_coff  = (const float*)d_in[4];
    const float* b_coff  = (const float*)d_in[5];
    const float* w_dconv = (const float*)d_in[6];
    const float* b_dconv = (const float*)d_in[7];
    float* out = (float*)d_out;

    ushort* x1t      = (ushort*)d_ws;              // 8388608 ushorts
    ushort* xft      = x1t + 8388608;              // 8388608
    ushort* off_feat = xft + 8388608;              // 8388608
    uint*   dyxp     = (uint*)(off_feat + 8388608);// 72*131072 uints
    ushort* mpl      = (ushort*)(dyxp + 9437184);  // 72*131072 ushorts
    ushort* wa1      = mpl + 9437184;              // 36864
    ushort* wa2      = wa1 + 36864;                // 147456
    ushort* wad      = wa2 + 147456;               // 36864

    to_gp_bf16<<<2048, 256, 0, stream>>>(cat_fea, x1t);
    to_gp_bf16<<<2048, 256, 0, stream>>>(f_fea, xft);
    prep_wa<<<(64 * 576 + 255) / 256, 256, 0, stream>>>(w_off2d, wa1, 64, 64);
    prep_wa<<<(256 * 576 + 255) / 256, 256, 0, stream>>>(w_coff, wa2, 216, 256);
    prep_wa<<<(64 * 576 + 255) / 256, 256, 0, stream>>>(w_dconv, wad, 64, 64);

    conv_pipe_k<1, 0><<<2048, 256, 0, stream>>>(x1t, wa1, b_off2d, off_feat,
                                                nullptr, nullptr, 64);
    conv_pipe_k<4, 1><<<2048, 256, 0, stream>>>(off_feat, wa2, b_coff, nullptr,
                                                dyxp, mpl, 216);
    deform_pipe_k<<<2048, 256, 0, stream>>>(xft, dyxp, mpl, wad, b_dconv, out);
}

// Round 6
// 151.841 us; speedup vs baseline: 14.5296x; 1.3915x over previous
//
#include <hip/hip_runtime.h>
#include <math.h>

typedef __attribute__((ext_vector_type(4))) float f32x4;
typedef __attribute__((ext_vector_type(8))) short bf16x8;

#define HH 128
#define WW 128
#define HWSZ 16384
#define BHW 131072
#define BB 8

__device__ __forceinline__ float bf2f(ushort u) {
    union { uint i; float f; } x; x.i = ((uint)u) << 16; return x.f;
}
__device__ __forceinline__ ushort f2bf(float f) {
    union { float f; uint i; } x; x.f = f;
    uint r = (x.i + 0x7fffu + ((x.i >> 16) & 1u)) >> 16;
    return (ushort)r;
}

// NCHW fp32 (C=64) -> group-planar bf16 xg[b][cg][hw][8].
__global__ __launch_bounds__(256) void to_gp_bf16(const float* __restrict__ x,
                                                  ushort* __restrict__ y) {
    __shared__ ushort lds[64][66];
    int blk = blockIdx.x;
    int b = blk >> 8;
    int hw0 = (blk & 255) << 6;
    int t = threadIdx.x;
    int lane = t & 63;
    int q = t >> 6;
#pragma unroll
    for (int i = 0; i < 16; i++) {
        int c = i * 4 + q;
        lds[c][lane] = f2bf(x[((size_t)(b * 64 + c) << 14) + hw0 + lane]);
    }
    __syncthreads();
#pragma unroll
    for (int it = 0; it < 2; it++) {
        int id = it * 256 + t;
        int cg = id >> 6;
        int px = id & 63;
        uint pk[4];
#pragma unroll
        for (int j = 0; j < 4; j++)
            pk[j] = (uint)lds[cg * 8 + 2 * j][px] | ((uint)lds[cg * 8 + 2 * j + 1][px] << 16);
        *(uint4*)(y + ((((size_t)b * 8 + cg) << 14) + hw0 + px) * 8) = *(uint4*)pk;
    }
}

// w[Co][64][3][3] fp32 -> wa[Co_pad][576] bf16 with r = kk*64+ci (zero-padded rows).
__global__ __launch_bounds__(256) void prep_wa(const float* __restrict__ w,
                                               ushort* __restrict__ wa, int Co, int Co_pad) {
    int idx = blockIdx.x * 256 + threadIdx.x;
    if (idx >= Co_pad * 576) return;
    int co = idx / 576, r = idx % 576;
    int kk = r >> 6, ci = r & 63;
    ushort v = 0;
    if (co < Co) v = f2bf(w[(co * 64 + ci) * 9 + kk]);
    wa[idx] = v;
}

// ---------------------------------------------------------------------------
// m97-style implicit-GEMM 3x3 conv: BK=64 (one 3x3 tap per K-step, 9 steps).
// A (weights, NCO*64 co) staged via global_load_lds (linear dest, pre-swizzled
// source); B (im2col 64px x 64ci) reg-staged with zero borders. Both tiles
// XOR-swizzled (row&7)<<4 against the 128B-stride bank conflict.
// MODE 0: output group-planar bf16. MODE 1: planar dyx + sigmoided mask.
// ---------------------------------------------------------------------------
template<int NCO, int MODE>
__global__ __launch_bounds__(256, 3) void conv_gemm2_k(
    const ushort* __restrict__ xt, const ushort* __restrict__ wa,
    const float* __restrict__ bias, ushort* __restrict__ y,
    uint* __restrict__ dyxp, ushort* __restrict__ mpl, int Cout) {
    __shared__ ushort Al[NCO * 64 * 64];   // [NCO*64 co][64 ci], row 128 B, swizzled
    __shared__ ushort Bt[64 * 64];         // [64 px][64 ci], row 128 B, swizzled
    int t = threadIdx.x;
    int orig = blockIdx.x;
    int blk = (orig & 7) * 256 + (orig >> 3);   // bijective, 2048 = 8*256; XCD = image
    int b = blk >> 8;
    int h = (blk >> 1) & 127;
    int w0 = (blk & 1) << 6;
    int lane = t & 63;
    int wv = t >> 6;
    int lg = lane >> 4;
    int lr = lane & 15;
    int rs = (lr & 7) << 4;                      // read-side swizzle
    int asw = ((lane & 7) ^ (lane >> 3)) << 4;   // source pre-swizzle for gload_lds
    const char* wab = (const char*)wa;

    f32x4 acc[NCO][4];
#pragma unroll
    for (int n = 0; n < NCO; n++)
#pragma unroll
        for (int j = 0; j < 4; j++) acc[n][j] = f32x4{0, 0, 0, 0};

#pragma unroll 1
    for (int kk = 0; kk < 9; kk++) {
        int ky = kk / 3;
        int kx = kk - ky * 3;
        __syncthreads();
        // ---- stage A: global_load_lds, 1024 B per wave-instr (8 rows) ----
#pragma unroll
        for (int a = 0; a < 2 * NCO; a++) {
            int rb = wv * (NCO * 16) + a * 8;
            const char* g = wab + (size_t)(rb + (lane >> 3)) * 1152 + kk * 128 + asw;
            __builtin_amdgcn_global_load_lds(
                (const __attribute__((address_space(1))) void*)g,
                (__attribute__((address_space(3))) void*)((char*)Al + rb * 128),
                16, 0, 0);
        }
        // ---- stage B: thread -> (px=lane, cg=wv and wv+4), zero at borders ----
        int hy = h + ky - 1;
        int wx = w0 + lane + kx - 1;
        bool val = ((unsigned)hy < 128u) && ((unsigned)wx < 128u);
        uint4 v0 = {0u, 0u, 0u, 0u}, v1 = {0u, 0u, 0u, 0u};
        if (val) {
            const ushort* gb = xt + ((((size_t)b * 8 + wv) << 14) + (hy << 7) + wx) * 8;
            v0 = *(const uint4*)gb;
            v1 = *(const uint4*)(gb + (4ull << 17));   // +4 cg planes
        }
        int swl = (lane & 7) << 4;
        *(uint4*)((char*)Bt + lane * 128 + ((wv * 16) ^ swl)) = v0;
        *(uint4*)((char*)Bt + lane * 128 + (((wv + 4) * 16) ^ swl)) = v1;
        __syncthreads();
        // ---- compute: per wave 32 MFMA, 16 ds_read_b128 ----
#pragma unroll
        for (int n = 0; n < NCO; n++) {
            int ar = n * 64 + wv * 16 + lr;
            bf16x8 a0 = *(const bf16x8*)((char*)Al + ar * 128 + ((lg * 16) ^ rs));
            bf16x8 a1 = *(const bf16x8*)((char*)Al + ar * 128 + ((lg * 16 + 64) ^ rs));
#pragma unroll
            for (int j = 0; j < 4; j++) {
                int pr = j * 16 + lr;
                bf16x8 b0 = *(const bf16x8*)((char*)Bt + pr * 128 + ((lg * 16) ^ rs));
                bf16x8 b1 = *(const bf16x8*)((char*)Bt + pr * 128 + ((lg * 16 + 64) ^ rs));
                acc[n][j] = __builtin_amdgcn_mfma_f32_16x16x32_bf16(a0, b0, acc[n][j], 0, 0, 0);
                acc[n][j] = __builtin_amdgcn_mfma_f32_16x16x32_bf16(a1, b1, acc[n][j], 0, 0, 0);
            }
        }
    }

    // ---- epilogue: D[co][px], co = n*64 + wv*16 + lg*4 + r, px = j*16 + lr ----
#pragma unroll
    for (int n = 0; n < NCO; n++) {
        int co_g = n * 64 + wv * 16 + lg * 4;
        if (co_g < Cout) {
            float bs[4];
#pragma unroll
            for (int r = 0; r < 4; r++) bs[r] = bias[co_g + r];
#pragma unroll
            for (int j = 0; j < 4; j++) {
                int pxl = j * 16 + lr;
                int hw = (h << 7) + w0 + pxl;
                int bhw = (b << 14) + hw;
                if (MODE == 0) {
                    int cg = co_g >> 3, cs = co_g & 7;
                    uint2 s2;
                    s2.x = (uint)f2bf(acc[n][j][0] + bs[0]) | ((uint)f2bf(acc[n][j][1] + bs[1]) << 16);
                    s2.y = (uint)f2bf(acc[n][j][2] + bs[2]) | ((uint)f2bf(acc[n][j][3] + bs[3]) << 16);
                    *(uint2*)(y + ((((size_t)b * 8 + cg) << 14) + hw) * 8 + cs) = s2;
                } else if (co_g < 144) {
                    int p0 = co_g >> 1;
                    uint u0 = (uint)f2bf(acc[n][j][0] + bs[0]) | ((uint)f2bf(acc[n][j][1] + bs[1]) << 16);
                    uint u1 = (uint)f2bf(acc[n][j][2] + bs[2]) | ((uint)f2bf(acc[n][j][3] + bs[3]) << 16);
                    dyxp[(size_t)p0 * BHW + bhw] = u0;
                    dyxp[(size_t)(p0 + 1) * BHW + bhw] = u1;
                } else {
#pragma unroll
                    for (int r = 0; r < 4; r++) {
                        float f = 1.f / (1.f + __expf(-(acc[n][j][r] + bs[r])));
                        mpl[(size_t)(co_g - 144 + r) * BHW + bhw] = f2bf(f);
                    }
                }
            }
        }
    }
}

// ---------------------------------------------------------------------------
// Modulated deformable conv, K-chunked double-buffered pipeline (unchanged).
// ---------------------------------------------------------------------------
__global__ __launch_bounds__(256, 3) void deform_pipe_k(
    const ushort* __restrict__ xg, const uint* __restrict__ dyxp,
    const ushort* __restrict__ mpl, const ushort* __restrict__ wa,
    const float* __restrict__ bias, float* __restrict__ out) {
    __shared__ ushort Bl[2 * 64 * 192];
    int t = threadIdx.x;
    int orig = blockIdx.x;
    int blk = (orig & 7) * 256 + (orig >> 3);   // bijective: 2048 = 8 * 256
    int b = blk >> 8;
    int h = (blk >> 1) & 127;
    int w0 = (blk & 1) << 6;
    int lane = t & 63;
    int wv = t >> 6;
    int lg = lane >> 4;
    int lr = lane & 15;
    int wgl = w0 + lane;
    int bhw = (b << 14) + (h << 7) + wgl;

    uint4 st[6];

#define SAMPLE(KR) do {                                                         \
    _Pragma("unroll")                                                           \
    for (int i = 0; i < 6; i++) {                                               \
        int u = i * 4 + wv;                                                     \
        int dg = u / 3;                                                         \
        int q = u - dg * 3;                                                     \
        int p = dg * 9 + (KR) * 3 + q;                                          \
        uint dyx = dyxp[(size_t)p * BHW + bhw];                                 \
        float m = bf2f(mpl[(size_t)p * BHW + bhw]);                             \
        float dy = bf2f((ushort)(dyx & 0xffff));                                \
        float dx = bf2f((ushort)(dyx >> 16));                                   \
        float py = dy + (float)(h + (KR) - 1);                                  \
        float px_ = dx + (float)(wgl + q - 1);                                  \
        float fy = floorf(py), fx = floorf(px_);                                \
        int y0 = (int)fy, x0 = (int)fx;                                         \
        int y1 = y0 + 1, x1 = x0 + 1;                                           \
        float ly = py - fy, lx = px_ - fx;                                      \
        bool vy0 = (unsigned)y0 < (unsigned)HH, vy1 = (unsigned)y1 < (unsigned)HH; \
        bool vx0 = (unsigned)x0 < (unsigned)WW, vx1 = (unsigned)x1 < (unsigned)WW; \
        float w00 = (vy0 && vx0) ? (1.f - ly) * (1.f - lx) * m : 0.f;           \
        float w01 = (vy0 && vx1) ? (1.f - ly) * lx * m : 0.f;                   \
        float w10 = (vy1 && vx0) ? ly * (1.f - lx) * m : 0.f;                   \
        float w11 = (vy1 && vx1) ? ly * lx * m : 0.f;                           \
        int y0c = min(max(y0, 0), HH - 1), y1c = min(max(y1, 0), HH - 1);       \
        int x0c = min(max(x0, 0), WW - 1), x1c = min(max(x1, 0), WW - 1);       \
        const ushort* gb = xg + (((size_t)b * 8 + dg) << 17);                   \
        uint4 q00 = *(const uint4*)(gb + ((y0c << 7) + x0c) * 8);               \
        uint4 q01 = *(const uint4*)(gb + ((y0c << 7) + x1c) * 8);               \
        uint4 q10 = *(const uint4*)(gb + ((y1c << 7) + x0c) * 8);               \
        uint4 q11 = *(const uint4*)(gb + ((y1c << 7) + x1c) * 8);               \
        const ushort* u00 = (const ushort*)&q00;                                \
        const ushort* u01 = (const ushort*)&q01;                                \
        const ushort* u10 = (const ushort*)&q10;                                \
        const ushort* u11 = (const ushort*)&q11;                                \
        uint pk[4];                                                             \
        _Pragma("unroll")                                                       \
        for (int c2 = 0; c2 < 4; c2++) {                                        \
            float v0 = w00 * bf2f(u00[2*c2])   + w01 * bf2f(u01[2*c2])          \
                     + w10 * bf2f(u10[2*c2])   + w11 * bf2f(u11[2*c2]);         \
            float v1 = w00 * bf2f(u00[2*c2+1]) + w01 * bf2f(u01[2*c2+1])        \
                     + w10 * bf2f(u10[2*c2+1]) + w11 * bf2f(u11[2*c2+1]);       \
            pk[c2] = (uint)f2bf(v0) | ((uint)f2bf(v1) << 16);                   \
        }                                                                       \
        st[i] = *(uint4*)pk;                                                    \
    } } while (0)

#define STAGE_WRITE(BI) do {                                                    \
    _Pragma("unroll")                                                           \
    for (int i = 0; i < 6; i++) {                                               \
        int u = i * 4 + wv;                                                     \
        int dg = u / 3;                                                         \
        int q = u - dg * 3;                                                     \
        int kb = (q * 128 + dg * 16) ^ ((lane & 7) << 4);                       \
        *(uint4*)((char*)Bl + (BI) * 24576 + lane * 384 + kb) = st[i];          \
    } } while (0)

    f32x4 acc[4] = {f32x4{0,0,0,0}, f32x4{0,0,0,0}, f32x4{0,0,0,0}, f32x4{0,0,0,0}};

#define MFMA_CHUNK(CH, BI) do {                                                 \
    _Pragma("unroll")                                                           \
    for (int c = 0; c < 6; c++) {                                               \
        bf16x8 a = *(const bf16x8*)(wa +                                        \
            (size_t)(wv * 16 + lr) * 576 + (CH) * 192 + c * 32 + lg * 8);       \
        _Pragma("unroll")                                                       \
        for (int j = 0; j < 4; j++) {                                           \
            int px = j * 16 + lr;                                               \
            int kb = (c * 64 + lg * 16) ^ ((px & 7) << 4);                      \
            bf16x8 bv = *(const bf16x8*)((char*)Bl + (BI) * 24576 + px * 384 + kb); \
            acc[j] = __builtin_amdgcn_mfma_f32_16x16x32_bf16(a, bv, acc[j], 0, 0, 0); \
        }                                                                       \
    } } while (0)

    SAMPLE(0);
    STAGE_WRITE(0);
    __syncthreads();

    SAMPLE(1);
    MFMA_CHUNK(0, 0);
    __syncthreads();
    STAGE_WRITE(1);
    __syncthreads();

    SAMPLE(2);
    MFMA_CHUNK(1, 1);
    __syncthreads();
    STAGE_WRITE(0);
    __syncthreads();

    MFMA_CHUNK(2, 0);

    // ---- epilogue: out NCHW fp32. D[co][px]: co = wv*16+lg*4+r, px = j*16+lr ----
    int co_g = wv * 16 + lg * 4;
    float bs[4];
#pragma unroll
    for (int r = 0; r < 4; r++) bs[r] = bias[co_g + r];
#pragma unroll
    for (int j = 0; j < 4; j++) {
        int pxl = j * 16 + lr;
        int hw = (h << 7) + w0 + pxl;
#pragma unroll
        for (int r = 0; r < 4; r++) {
            out[((size_t)(b * 64 + co_g + r) << 14) + hw] = acc[j][r] + bs[r];
        }
    }
#undef SAMPLE
#undef STAGE_WRITE
#undef MFMA_CHUNK
}

extern "C" void kernel_launch(void* const* d_in, const int* in_sizes, int n_in,
                              void* d_out, int out_size, void* d_ws, size_t ws_size,
                              hipStream_t stream) {
    const float* cat_fea = (const float*)d_in[0];
    const float* f_fea   = (const float*)d_in[1];
    const float* w_off2d = (const float*)d_in[2];
    const float* b_off2d = (const float*)d_in[3];
    const float* w_coff  = (const float*)d_in[4];
    const float* b_coff  = (const float*)d_in[5];
    const float* w_dconv = (const float*)d_in[6];
    const float* b_dconv = (const float*)d_in[7];
    float* out = (float*)d_out;

    ushort* x1t      = (ushort*)d_ws;              // 8388608 ushorts
    ushort* xft      = x1t + 8388608;              // 8388608
    ushort* off_feat = xft + 8388608;              // 8388608
    uint*   dyxp     = (uint*)(off_feat + 8388608);// 72*131072 uints
    ushort* mpl      = (ushort*)(dyxp + 9437184);  // 72*131072 ushorts
    ushort* wa1      = mpl + 9437184;              // 36864
    ushort* wa2      = wa1 + 36864;                // 147456
    ushort* wad      = wa2 + 147456;               // 36864

    to_gp_bf16<<<2048, 256, 0, stream>>>(cat_fea, x1t);
    to_gp_bf16<<<2048, 256, 0, stream>>>(f_fea, xft);
    prep_wa<<<(64 * 576 + 255) / 256, 256, 0, stream>>>(w_off2d, wa1, 64, 64);
    prep_wa<<<(256 * 576 + 255) / 256, 256, 0, stream>>>(w_coff, wa2, 216, 256);
    prep_wa<<<(64 * 576 + 255) / 256, 256, 0, stream>>>(w_dconv, wad, 64, 64);

    conv_gemm2_k<1, 0><<<2048, 256, 0, stream>>>(x1t, wa1, b_off2d, off_feat,
                                                 nullptr, nullptr, 64);
    conv_gemm2_k<4, 1><<<2048, 256, 0, stream>>>(off_feat, wa2, b_coff, nullptr,
                                                 dyxp, mpl, 216);
    deform_pipe_k<<<2048, 256, 0, stream>>>(xft, dyxp, mpl, wad, b_dconv, out);
}